// Round 6
// baseline (365.402 us; speedup 1.0000x reference)
//
#include <hip/hip_runtime.h>
#include <hip/hip_bf16.h>
#include <math.h>

#define B_  256
#define N_  80
#define C_  1024
#define CO_ 1024

typedef __hip_bfloat16 bf16;
using bf16x8 = __attribute__((ext_vector_type(8))) short;   // 8 bf16 = 4 VGPRs
using f32x4  = __attribute__((ext_vector_type(4))) float;

__device__ __forceinline__ float leaky(float v){ return v >= 0.f ? v : 0.2f * v; }
__device__ __forceinline__ float sigmoidf_(float v){ return 1.f / (1.f + __expf(-v)); }

__device__ __forceinline__ void gll16(const void* g, void* l){
    __builtin_amdgcn_global_load_lds(
        (const __attribute__((address_space(1))) void*)g,
        (__attribute__((address_space(3))) void*)l, 16, 0, 0);
}

// ---------------- K0: transpose+convert both weights: WT[n][k]=bf16(W[k][n]) --
__global__ __launch_bounds__(256) void k_convT2(const float* __restrict__ W0, const float* __restrict__ W1,
                                                bf16* __restrict__ T0, bf16* __restrict__ T1){
    __shared__ float t[32][33];
    const float* W = blockIdx.z ? W1 : W0;
    bf16* WT = blockIdx.z ? T1 : T0;
    int k0 = blockIdx.y * 32, n0 = blockIdx.x * 32;
    int tx = threadIdx.x & 31, ty = threadIdx.x >> 5;
    for (int i = ty; i < 32; i += 8) t[i][tx] = W[(size_t)(k0 + i) * 1024 + n0 + tx];
    __syncthreads();
    for (int i = ty; i < 32; i += 8)
        WT[(size_t)(n0 + i) * 1024 + k0 + tx] = __float2bfloat16(t[tx][i]);
}

// ---------------- K0b: ccwb = bf16(ccw), [80][2048] ----------------
__global__ void k_cvt_ccw(const float* __restrict__ ccw, bf16* __restrict__ ccwb){
    int i = blockIdx.x * 256 + threadIdx.x;
    ccwb[i] = __float2bfloat16(ccw[i]);
}

// ---------------- K1: adj_s (bf16, [80][88] padded rows) ----------------
__global__ void k_adj(const float* __restrict__ A, bf16* __restrict__ adjb){
    __shared__ float d[N_];
    int t = threadIdx.x;
    if (t < N_){
        float s = 0.f;
        for (int j = 0; j < N_; j++) s += A[t * N_ + j];
        d[t] = rsqrtf(s);
    }
    __syncthreads();
    for (int idx = t; idx < N_ * N_; idx += 256){
        int i = idx / N_, j = idx - i * N_;
        adjb[i * 88 + j] = __float2bfloat16(d[i] * A[j * N_ + i] * d[j]);
    }
}

// ---------------- K2/K12: h = bf16(leaky(A[80x80] @ X[80x1024])) via MFMA ----
template<int MODE>
__global__ __launch_bounds__(256) void k_prop_mfma(const void* __restrict__ srcv,
                                                   const bf16* __restrict__ Ag_,
                                                   bf16* __restrict__ H){
    __shared__ bf16 Btl[256 * 88];
    __shared__ bf16 Al [80 * 88];
    int b = blockIdx.x, c0 = blockIdx.y * 256, tid = threadIdx.x;
    int wave = tid >> 6, lane = tid & 63;
    int l15 = lane & 15, hi = lane >> 4;

    const bf16* Ag = Ag_ + (MODE ? (size_t)b * 80 * 88 : 0);
    #pragma unroll
    for (int k = 0; k < 4; k++){
        int cb = wave * 64 + 256 * k;
        if (cb + lane < 880)
            gll16(Ag + (size_t)(cb + lane) * 8, Al + (size_t)cb * 8);
    }
    if (MODE == 0){
        const float* xb = (const float*)srcv + (size_t)b * 81920 + c0;
        #pragma unroll
        for (int g = 0; g < 20; g++){
            int qq = g * 256 + tid;
            int m  = qq >> 6;
            int c4 = (qq & 63) * 4;
            float4 v = *(const float4*)(xb + (size_t)m * 1024 + c4);
            Btl[(c4 + 0) * 88 + m] = __float2bfloat16(v.x);
            Btl[(c4 + 1) * 88 + m] = __float2bfloat16(v.y);
            Btl[(c4 + 2) * 88 + m] = __float2bfloat16(v.z);
            Btl[(c4 + 3) * 88 + m] = __float2bfloat16(v.w);
        }
    } else {
        const bf16* xb = (const bf16*)srcv + (size_t)b * 81920 + c0;
        #pragma unroll
        for (int g = 0; g < 10; g++){
            int qq = g * 256 + tid;
            int m  = qq >> 5;
            int c8 = (qq & 31) * 8;
            union { bf16x8 v; bf16 e[8]; } u;
            u.v = *(const bf16x8*)(xb + (size_t)m * 1024 + c8);
            #pragma unroll
            for (int uu = 0; uu < 8; uu++) Btl[(c8 + uu) * 88 + m] = u.e[uu];
        }
    }
    __syncthreads();

    f32x4 acc[5][4];
    #pragma unroll
    for (int i = 0; i < 5; i++)
        #pragma unroll
        for (int j = 0; j < 4; j++) acc[i][j] = (f32x4){0.f, 0.f, 0.f, 0.f};

    #pragma unroll
    for (int ks = 0; ks < 3; ks++){
        bf16x8 a[5], bv[4];
        if (ks < 2){
            int k0 = ks * 32;
            #pragma unroll
            for (int i = 0; i < 5; i++)
                a[i] = *(const bf16x8*)(Al + (i * 16 + l15) * 88 + k0 + hi * 8);
            #pragma unroll
            for (int j = 0; j < 4; j++)
                bv[j] = *(const bf16x8*)(Btl + (wave * 64 + j * 16 + l15) * 88 + k0 + hi * 8);
        } else {
            int koff = (hi < 2) ? 64 + hi * 8 : 0;
            #pragma unroll
            for (int i = 0; i < 5; i++){
                bf16x8 v = *(const bf16x8*)(Al + (i * 16 + l15) * 88 + koff);
                if (hi >= 2) v = 0;
                a[i] = v;
            }
            #pragma unroll
            for (int j = 0; j < 4; j++){
                bf16x8 v = *(const bf16x8*)(Btl + (wave * 64 + j * 16 + l15) * 88 + koff);
                if (hi >= 2) v = 0;
                bv[j] = v;
            }
        }
        #pragma unroll
        for (int i = 0; i < 5; i++)
            #pragma unroll
            for (int j = 0; j < 4; j++)
                acc[i][j] = __builtin_amdgcn_mfma_f32_16x16x32_bf16(a[i], bv[j], acc[i][j], 0, 0, 0);
    }

    #pragma unroll
    for (int i = 0; i < 5; i++){
        #pragma unroll
        for (int r = 0; r < 4; r++){
            int orow = i * 16 + hi * 4 + r;
            #pragma unroll
            for (int j = 0; j < 4; j++){
                int ocol = c0 + wave * 64 + j * 16 + l15;
                H[(size_t)b * 81920 + (size_t)orow * 1024 + ocol] =
                    __float2bfloat16(leaky(acc[i][j][r]));
            }
        }
    }
}

// ---------------- K3/K13: 256x256 bf16 MFMA GEMM, 4-phase, dbuf BK=64 --------
// 8 waves (2M x 4N); per-wave out 128x64; K=1024 -> 16 K-tiles.
// Swizzle (both-sides): LDS slot s holds global k-slot s^(r&7); reads use
// slot = S^(row&7) -> 2-way bank alias (free). gll16 dest stays linear.
// Grid 320 = 8 XCDs x 40 (10 row-tiles x 4 col-tiles each).
template<int EPI>
__global__ __launch_bounds__(512, 1) void k_gemm_256(const bf16* __restrict__ Abf,
                                                     const bf16* __restrict__ WT,
                                                     const float* __restrict__ Res,
                                                     void* __restrict__ Outv){
    __shared__ alignas(16) bf16 As[2][256 * 64];
    __shared__ alignas(16) bf16 Bs[2][256 * 64];
    const int K = 1024;
    const int NT = 16;
    int tid = threadIdx.x;
    int wave = tid >> 6, lane = tid & 63;
    int l15 = lane & 15, hi = lane >> 4;
    int wm = wave >> 2, wn = wave & 3;

    int bid = blockIdx.x;
    int xcd = bid & 7, idx = bid >> 3;              // idx 0..39
    int row0 = (xcd * 10 + (idx >> 2)) * 256;       // 80 row-tiles
    int col0 = (idx & 3) * 256;                     // 4 col-tiles

    // staging: thread t handles chunks t+g*512; chunk c -> (r=c>>3, lds slot c&7)
    // source pre-swizzle: global k-slot = (t&7)^((t>>3)&7)  (g-invariant)
    int sr = tid >> 3;
    int sq = (tid & 7) ^ (sr & 7);
    const bf16* gA = Abf + (size_t)(row0 + sr) * K + sq * 8;
    const bf16* gB = WT  + (size_t)(col0 + sr) * K + sq * 8;

    f32x4 acc[8][4];
    #pragma unroll
    for (int i = 0; i < 8; i++)
        #pragma unroll
        for (int j = 0; j < 4; j++) acc[i][j] = (f32x4){0.f, 0.f, 0.f, 0.f};

    auto STAGE = [&](int kt, int bf){
        int k0 = kt * 64;
        bf16* da = &As[bf][wave * 512];
        bf16* db = &Bs[bf][wave * 512];
        #pragma unroll
        for (int g = 0; g < 4; g++){
            gll16(gA + k0 + (size_t)g * 64 * K, da + g * 4096);
            gll16(gB + k0 + (size_t)g * 64 * K, db + g * 4096);
        }
    };

    STAGE(0, 0);
    asm volatile("s_waitcnt vmcnt(0)" ::: "memory");
    __builtin_amdgcn_s_barrier();

    int baseA = (wm * 128 + l15) * 64;   // + il*1024 (+4096 for ih=1) + slot*8
    int baseB = (wn * 64  + l15) * 64;   // + jl*1024 (+2048 for jh=1)
    int sx = l15 & 7;

    bf16x8 a[4][2], b0[2][2], b1[2][2];

    for (int kt = 0; kt < NT; ++kt){
        int bf = kt & 1;
        const bf16* SA = &As[bf][0];
        const bf16* SB = &Bs[bf][0];

        // ---- P1: stage kt+1; read A(ih=0) + B(jh=0); MFMA Q00
        if (kt + 1 < NT) STAGE(kt + 1, bf ^ 1);
        #pragma unroll
        for (int il = 0; il < 4; il++)
            #pragma unroll
            for (int kk = 0; kk < 2; kk++)
                a[il][kk] = *(const bf16x8*)(SA + baseA + il * 1024 + (((kk * 4 + hi) ^ sx) << 3));
        #pragma unroll
        for (int jl = 0; jl < 2; jl++)
            #pragma unroll
            for (int kk = 0; kk < 2; kk++)
                b0[jl][kk] = *(const bf16x8*)(SB + baseB + jl * 1024 + (((kk * 4 + hi) ^ sx) << 3));
        asm volatile("s_waitcnt lgkmcnt(0)" ::: "memory");
        __builtin_amdgcn_sched_barrier(0);
        __builtin_amdgcn_s_setprio(1);
        #pragma unroll
        for (int il = 0; il < 4; il++)
            #pragma unroll
            for (int jl = 0; jl < 2; jl++)
                #pragma unroll
                for (int kk = 0; kk < 2; kk++)
                    acc[il][jl] = __builtin_amdgcn_mfma_f32_16x16x32_bf16(a[il][kk], b0[jl][kk], acc[il][jl], 0, 0, 0);
        __builtin_amdgcn_s_setprio(0);
        __builtin_amdgcn_s_barrier();

        // ---- P2: read B(jh=1); MFMA Q01 (A regs reused)
        #pragma unroll
        for (int jl = 0; jl < 2; jl++)
            #pragma unroll
            for (int kk = 0; kk < 2; kk++)
                b1[jl][kk] = *(const bf16x8*)(SB + baseB + 2048 + jl * 1024 + (((kk * 4 + hi) ^ sx) << 3));
        asm volatile("s_waitcnt lgkmcnt(0)" ::: "memory");
        __builtin_amdgcn_sched_barrier(0);
        __builtin_amdgcn_s_setprio(1);
        #pragma unroll
        for (int il = 0; il < 4; il++)
            #pragma unroll
            for (int jl = 0; jl < 2; jl++)
                #pragma unroll
                for (int kk = 0; kk < 2; kk++)
                    acc[il][2 + jl] = __builtin_amdgcn_mfma_f32_16x16x32_bf16(a[il][kk], b1[jl][kk], acc[il][2 + jl], 0, 0, 0);
        __builtin_amdgcn_s_setprio(0);
        __builtin_amdgcn_s_barrier();

        // ---- P3: read A(ih=1); MFMA Q11 (B1 reused)
        #pragma unroll
        for (int il = 0; il < 4; il++)
            #pragma unroll
            for (int kk = 0; kk < 2; kk++)
                a[il][kk] = *(const bf16x8*)(SA + baseA + 4096 + il * 1024 + (((kk * 4 + hi) ^ sx) << 3));
        asm volatile("s_waitcnt lgkmcnt(0)" ::: "memory");
        __builtin_amdgcn_sched_barrier(0);
        __builtin_amdgcn_s_setprio(1);
        #pragma unroll
        for (int il = 0; il < 4; il++)
            #pragma unroll
            for (int jl = 0; jl < 2; jl++)
                #pragma unroll
                for (int kk = 0; kk < 2; kk++)
                    acc[4 + il][2 + jl] = __builtin_amdgcn_mfma_f32_16x16x32_bf16(a[il][kk], b1[jl][kk], acc[4 + il][2 + jl], 0, 0, 0);
        __builtin_amdgcn_s_setprio(0);
        __builtin_amdgcn_s_barrier();

        // ---- P4: MFMA Q10 (A1 x B0, all regs); then publish next buffer
        __builtin_amdgcn_s_setprio(1);
        #pragma unroll
        for (int il = 0; il < 4; il++)
            #pragma unroll
            for (int jl = 0; jl < 2; jl++)
                #pragma unroll
                for (int kk = 0; kk < 2; kk++)
                    acc[4 + il][jl] = __builtin_amdgcn_mfma_f32_16x16x32_bf16(a[il][kk], b0[jl][kk], acc[4 + il][jl], 0, 0, 0);
        __builtin_amdgcn_s_setprio(0);
        asm volatile("s_waitcnt vmcnt(0)" ::: "memory");
        __builtin_amdgcn_s_barrier();
    }

    int orow = row0 + wm * 128 + hi * 4;
    int ocol = col0 + wn * 64 + l15;
    #pragma unroll
    for (int i = 0; i < 8; i++){
        #pragma unroll
        for (int r = 0; r < 4; r++){
            int rr = orow + i * 16 + r;
            #pragma unroll
            for (int j = 0; j < 4; j++){
                size_t o = (size_t)rr * 1024 + ocol + j * 16;
                float v = acc[i][j][r];
                if (EPI == 0) ((bf16*)Outv)[o] = __float2bfloat16(v + Res[o]);
                else          ((float*)Outv)[o] = leaky(v);
            }
        }
    }
}

// ---------------- K5: Out = A @ W^T + bias (small, fp32) ----------------
#define PAD 68
__global__ __launch_bounds__(256) void k_gemm_bt_bias(const float* __restrict__ Am,
                                                      const float* __restrict__ W,
                                                      const float* __restrict__ bias,
                                                      float* __restrict__ Out, int M){
    __shared__ float As[16][PAD];
    __shared__ float Bs[16][PAD];
    int tid = threadIdx.x;
    int tx = tid & 15, ty = tid >> 4;
    int row0 = blockIdx.y * 64, col0 = blockIdx.x * 64;
    float acc[4][4] = {};
    int lr = tid >> 2;
    int lk = (tid & 3) * 4;
    for (int k0 = 0; k0 < C_; k0 += 16){
        float4 av = *(const float4*)(Am + (size_t)(row0 + lr) * C_ + k0 + lk);
        float4 wv = *(const float4*)(W  + (size_t)(col0 + lr) * C_ + k0 + lk);
        As[lk + 0][lr] = av.x; As[lk + 1][lr] = av.y;
        As[lk + 2][lr] = av.z; As[lk + 3][lr] = av.w;
        Bs[lk + 0][lr] = wv.x; Bs[lk + 1][lr] = wv.y;
        Bs[lk + 2][lr] = wv.z; Bs[lk + 3][lr] = wv.w;
        __syncthreads();
        #pragma unroll
        for (int kk = 0; kk < 16; kk++){
            float4 a  = *(const float4*)&As[kk][ty * 4];
            float4 bb = *(const float4*)&Bs[kk][tx * 4];
            float ar[4] = {a.x, a.y, a.z, a.w};
            float br[4] = {bb.x, bb.y, bb.z, bb.w};
            #pragma unroll
            for (int i = 0; i < 4; i++)
                #pragma unroll
                for (int j = 0; j < 4; j++) acc[i][j] += ar[i] * br[j];
        }
        __syncthreads();
    }
    for (int i = 0; i < 4; i++){
        int r = row0 + ty * 4 + i;
        for (int j = 0; j < 4; j++){
            int cl = col0 + tx * 4 + j;
            Out[(size_t)r * C_ + cl] = acc[i][j] + bias[cl];
        }
    }
}

// ---------------- K4: glb0[b,c] = mean_n x2b[b,n,c] ----------------
__global__ void k_pool(const bf16* __restrict__ X2b, float* __restrict__ glb0){
    int b = blockIdx.x, c = blockIdx.y * 256 + threadIdx.x;
    const bf16* p = X2b + (size_t)b * 81920 + c;
    float s = 0.f;
    for (int nn = 0; nn < N_; nn++) s += __bfloat162float(p[nn * 1024]);
    glb0[b * C_ + c] = s * (1.f / N_);
}

// ---------------- K6: BN stats over batch ----------------
__global__ void k_bnstat(const float* __restrict__ g, float* __restrict__ mu,
                         float* __restrict__ rstd){
    int c = blockIdx.x * 256 + threadIdx.x;
    float s = 0.f, s2 = 0.f;
    for (int b = 0; b < B_; b++){ float v = g[b * C_ + c]; s += v; s2 += v * v; }
    float m = s * (1.f / B_);
    float var = s2 * (1.f / B_) - m * m;
    mu[c] = m;
    rstd[c] = rsqrtf(var + 1e-5f);
}

// ---------------- K7: glb2b = bf16(leaky(BN(glb1))) ----------------
__global__ void k_bnapply(const float* __restrict__ g, const float* __restrict__ mu,
                          const float* __restrict__ rstd, const float* __restrict__ gamma,
                          const float* __restrict__ beta, bf16* __restrict__ o){
    int i = blockIdx.x * 256 + threadIdx.x;
    int c = i & (C_ - 1);
    float v = (g[i] - mu[c]) * rstd[c] * gamma[c] + beta[c];
    o[i] = __float2bfloat16(leaky(v));
}

// ---------------- K9: fused dyn = sigmoid(ccw@[glb2;x2^T]+ccb) + loss + ADJD -
// 5 waves. Scores stay in LDS S[80][81]; DYN never hits HBM.
__global__ __launch_bounds__(320) void k_dyn_fused(const bf16* __restrict__ X2b,
                                                   const bf16* __restrict__ ccwb,
                                                   const bf16* __restrict__ glb2b,
                                                   const float* __restrict__ ccb,
                                                   const float* __restrict__ out1,
                                                   bf16* __restrict__ ADJD,
                                                   float* __restrict__ lossp){
    __shared__ alignas(16) bf16 At[80 * 32];
    __shared__ alignas(16) bf16 Bt[80 * 32];
    __shared__ float S[80][81];
    __shared__ float di_s[80], o1s[80], dd[80];
    int b = blockIdx.x, tid = threadIdx.x;
    int wave = tid >> 6, lane = tid & 63;
    int l15 = lane & 15, hi = lane >> 4;

    const bf16* gA = ccwb + (size_t)(wave * 16 + (lane >> 2)) * 2048 + (lane & 3) * 8;
    const bf16* gB = X2b + ((size_t)b * 80 + wave * 16 + (lane >> 2)) * 1024 + (lane & 3) * 8;
    const bf16* gG = glb2b + (size_t)b * 1024;
    bf16* dA = At + wave * 512;
    bf16* dB = Bt + wave * 512;

    f32x4 acc[5];
    #pragma unroll
    for (int j = 0; j < 5; j++) acc[j] = (f32x4){0.f, 0.f, 0.f, 0.f};

    for (int k0 = 0; k0 < 2048; k0 += 32){
        gll16(gA + k0, dA);
        if (k0 >= 1024) gll16(gB + (k0 - 1024), dB);
        __syncthreads();
        bf16x8 a = *(const bf16x8*)(At + (wave * 16 + l15) * 32 + hi * 8);
        bf16x8 bv[5];
        if (k0 < 1024){
            bf16x8 g = *(const bf16x8*)(gG + k0 + hi * 8);
            #pragma unroll
            for (int j = 0; j < 5; j++) bv[j] = g;
        } else {
            #pragma unroll
            for (int j = 0; j < 5; j++)
                bv[j] = *(const bf16x8*)(Bt + (j * 16 + l15) * 32 + hi * 8);
        }
        #pragma unroll
        for (int j = 0; j < 5; j++)
            acc[j] = __builtin_amdgcn_mfma_f32_16x16x32_bf16(a, bv[j], acc[j], 0, 0, 0);
        __syncthreads();
    }

    #pragma unroll
    for (int r = 0; r < 4; r++){
        int n = wave * 16 + hi * 4 + r;
        float cb = ccb[n];
        #pragma unroll
        for (int j = 0; j < 5; j++)
            S[n][j * 16 + l15] = sigmoidf_(acc[j][r] + cb);
    }
    __syncthreads();
    if (tid < 80){
        float rs = 0.f;
        for (int m = 0; m < 80; m++) rs += S[tid][m];
        di_s[tid] = rsqrtf(rs);
        o1s[tid] = sigmoidf_(out1[b * 80 + tid]);
    }
    __syncthreads();
    if (tid < 80){
        float cs = 0.f;
        for (int n = 0; n < 80; n++) cs += o1s[n] * S[n][tid];
        float diff = o1s[tid] - cs * (1.f / 80.f);
        dd[tid] = diff * diff;
    }
    __syncthreads();
    if (tid == 0){
        float s = 0.f;
        for (int m = 0; m < 80; m++) s += dd[m];
        lossp[b] = sqrtf(s);
    }
    bf16* ab = ADJD + (size_t)b * 80 * 88;
    for (int idx = tid; idx < 6400; idx += 320){
        int n = idx / 80, m = idx - n * 80;
        ab[n * 88 + m] = __float2bfloat16(di_s[n] * S[m][n] * di_s[m]);
    }
}

// ---------------- K11: loss = sum(lossp) ----------------
__global__ void k_lsum(const float* __restrict__ lossp, float* __restrict__ out_loss){
    float v = lossp[threadIdx.x];
    for (int off = 32; off; off >>= 1) v += __shfl_down(v, off);
    __shared__ float wsum[4];
    int lane = threadIdx.x & 63, w = threadIdx.x >> 6;
    if (lane == 0) wsum[w] = v;
    __syncthreads();
    if (threadIdx.x == 0) out_loss[0] = wsum[0] + wsum[1] + wsum[2] + wsum[3];
}

extern "C" void kernel_launch(void* const* d_in, const int* in_sizes, int n_in,
                              void* d_out, int out_size, void* d_ws, size_t ws_size,
                              hipStream_t stream) {
    const float* x     = (const float*)d_in[0];
    const float* out1  = (const float*)d_in[1];
    const float* A     = (const float*)d_in[2];
    const float* sw    = (const float*)d_in[3];
    const float* cgw   = (const float*)d_in[4];
    const float* cgb   = (const float*)d_in[5];
    const float* gamma = (const float*)d_in[6];
    const float* beta  = (const float*)d_in[7];
    const float* ccw   = (const float*)d_in[8];
    const float* ccb   = (const float*)d_in[9];
    const float* dw    = (const float*)d_in[10];
    float* out = (float*)d_out;

    const size_t XN = (size_t)B_ * N_ * C_;   // 20,971,520
    char* p = (char*)d_ws;
    bf16*  Hbf  = (bf16*)p;   p += XN * 2;               // 42 MB
    bf16*  X2b  = (bf16*)p;   p += XN * 2;               // 42 MB
    bf16*  SWT  = (bf16*)p;   p += (size_t)C_ * C_ * 2;  // 2 MB
    bf16*  DWT  = (bf16*)p;   p += (size_t)C_ * CO_ * 2; // 2 MB
    bf16*  CCWB = (bf16*)p;   p += (size_t)N_ * 2048 * 2;
    bf16*  ADJS = (bf16*)p;   p += (size_t)80 * 88 * 2;
    bf16*  ADJD = (bf16*)p;   p += (size_t)B_ * 80 * 88 * 2;  // 3.6 MB
    float* GLB0 = (float*)p;  p += (size_t)B_ * C_ * 4;
    float* GLB1 = (float*)p;  p += (size_t)B_ * C_ * 4;
    bf16*  GLB2 = (bf16*)p;   p += (size_t)B_ * C_ * 2;
    float* MU   = (float*)p;  p += C_ * 4;
    float* RSTD = (float*)p;  p += C_ * 4;
    float* LOSSP= (float*)p;  p += B_ * 4;

    k_convT2<<<dim3(32, 32, 2), 256, 0, stream>>>(sw, dw, SWT, DWT);
    k_cvt_ccw<<<(N_ * 2048) / 256, 256, 0, stream>>>(ccw, CCWB);
    k_adj<<<1, 256, 0, stream>>>(A, ADJS);
    k_prop_mfma<0><<<dim3(B_, 4), 256, 0, stream>>>(x, ADJS, Hbf);
    k_gemm_256<0><<<320, 512, 0, stream>>>(Hbf, SWT, x, X2b);
    k_pool<<<dim3(B_, C_ / 256), 256, 0, stream>>>(X2b, GLB0);
    k_gemm_bt_bias<<<dim3(C_ / 64, B_ / 64), 256, 0, stream>>>(GLB0, cgw, cgb, GLB1, B_);
    k_bnstat<<<C_ / 256, 256, 0, stream>>>(GLB1, MU, RSTD);
    k_bnapply<<<(B_ * C_) / 256, 256, 0, stream>>>(GLB1, MU, RSTD, gamma, beta, GLB2);
    k_dyn_fused<<<B_, 320, 0, stream>>>(X2b, CCWB, GLB2, ccb, out1, ADJD, LOSSP);
    k_lsum<<<1, 256, 0, stream>>>(LOSSP, out + (size_t)B_ * N_ * CO_);
    k_prop_mfma<1><<<dim3(B_, 4), 256, 0, stream>>>(X2b, ADJD, Hbf);
    k_gemm_256<1><<<320, 512, 0, stream>>>(Hbf, DWT, nullptr, out);
}

// Round 7
// 272.532 us; speedup vs baseline: 1.3408x; 1.3408x over previous
//
#include <hip/hip_runtime.h>
#include <hip/hip_bf16.h>
#include <math.h>

#define B_  256
#define N_  80
#define C_  1024
#define CO_ 1024

typedef __hip_bfloat16 bf16;
using bf16x8 = __attribute__((ext_vector_type(8))) short;   // 8 bf16 = 4 VGPRs
using f32x4  = __attribute__((ext_vector_type(4))) float;

__device__ __forceinline__ float leaky(float v){ return v >= 0.f ? v : 0.2f * v; }
__device__ __forceinline__ float sigmoidf_(float v){ return 1.f / (1.f + __expf(-v)); }

__device__ __forceinline__ void gll16(const void* g, void* l){
    __builtin_amdgcn_global_load_lds(
        (const __attribute__((address_space(1))) void*)g,
        (__attribute__((address_space(3))) void*)l, 16, 0, 0);
}

// ---------------- K0: transpose+convert both weights: WT[n][k]=bf16(W[k][n]) --
__global__ __launch_bounds__(256) void k_convT2(const float* __restrict__ W0, const float* __restrict__ W1,
                                                bf16* __restrict__ T0, bf16* __restrict__ T1){
    __shared__ float t[32][33];
    const float* W = blockIdx.z ? W1 : W0;
    bf16* WT = blockIdx.z ? T1 : T0;
    int k0 = blockIdx.y * 32, n0 = blockIdx.x * 32;
    int tx = threadIdx.x & 31, ty = threadIdx.x >> 5;
    for (int i = ty; i < 32; i += 8) t[i][tx] = W[(size_t)(k0 + i) * 1024 + n0 + tx];
    __syncthreads();
    for (int i = ty; i < 32; i += 8)
        WT[(size_t)(n0 + i) * 1024 + k0 + tx] = __float2bfloat16(t[tx][i]);
}

// ---------------- K0b: plain casts ----------------
__global__ void k_cvt_ccw(const float* __restrict__ ccw, bf16* __restrict__ ccwb){
    int i = blockIdx.x * 256 + threadIdx.x;
    ccwb[i] = __float2bfloat16(ccw[i]);
}
__global__ void k_cvt4(const float* __restrict__ src, bf16* __restrict__ dst){
    int i = (blockIdx.x * 256 + threadIdx.x) * 4;
    float4 v = *(const float4*)(src + i);
    dst[i + 0] = __float2bfloat16(v.x);
    dst[i + 1] = __float2bfloat16(v.y);
    dst[i + 2] = __float2bfloat16(v.z);
    dst[i + 3] = __float2bfloat16(v.w);
}

// ---------------- K1: adj_s (bf16, [80][88] padded rows) ----------------
__global__ void k_adj(const float* __restrict__ A, bf16* __restrict__ adjb){
    __shared__ float d[N_];
    int t = threadIdx.x;
    if (t < N_){
        float s = 0.f;
        for (int j = 0; j < N_; j++) s += A[t * N_ + j];
        d[t] = rsqrtf(s);
    }
    __syncthreads();
    for (int idx = t; idx < N_ * N_; idx += 256){
        int i = idx / N_, j = idx - i * N_;
        adjb[i * 88 + j] = __float2bfloat16(d[i] * A[j * N_ + i] * d[j]);
    }
}

// ---------------- K2/K12: h = bf16(leaky(A[80x80] @ X[80x1024])) via MFMA ----
// MODE 0: X = x (fp32), A = static adj.  MODE 1: X = X2b (bf16), A = ADJD[b].
template<int MODE>
__global__ __launch_bounds__(256) void k_prop_mfma(const void* __restrict__ srcv,
                                                   const bf16* __restrict__ Ag_,
                                                   bf16* __restrict__ H){
    __shared__ bf16 Btl[256 * 88];
    __shared__ bf16 Al [80 * 88];
    int b = blockIdx.x, c0 = blockIdx.y * 256, tid = threadIdx.x;
    int wave = tid >> 6, lane = tid & 63;
    int l15 = lane & 15, hi = lane >> 4;

    const bf16* Ag = Ag_ + (MODE ? (size_t)b * 80 * 88 : 0);
    #pragma unroll
    for (int k = 0; k < 4; k++){
        int cb = wave * 64 + 256 * k;
        if (cb + lane < 880)
            gll16(Ag + (size_t)(cb + lane) * 8, Al + (size_t)cb * 8);
    }
    // column-per-thread transpose staging (r4 pattern: coalesced global reads)
    {
        size_t rowbase = (size_t)b * 81920 + c0 + tid;
        #pragma unroll 8
        for (int m = 0; m < 80; m++){
            bf16 h;
            if (MODE == 0) h = __float2bfloat16(((const float*)srcv)[rowbase + (size_t)m * 1024]);
            else           h = ((const bf16*)srcv)[rowbase + (size_t)m * 1024];
            Btl[tid * 88 + m] = h;
        }
    }
    __syncthreads();

    f32x4 acc[5][4];
    #pragma unroll
    for (int i = 0; i < 5; i++)
        #pragma unroll
        for (int j = 0; j < 4; j++) acc[i][j] = (f32x4){0.f, 0.f, 0.f, 0.f};

    #pragma unroll
    for (int ks = 0; ks < 3; ks++){
        bf16x8 a[5], bv[4];
        if (ks < 2){
            int k0 = ks * 32;
            #pragma unroll
            for (int i = 0; i < 5; i++)
                a[i] = *(const bf16x8*)(Al + (i * 16 + l15) * 88 + k0 + hi * 8);
            #pragma unroll
            for (int j = 0; j < 4; j++)
                bv[j] = *(const bf16x8*)(Btl + (wave * 64 + j * 16 + l15) * 88 + k0 + hi * 8);
        } else {
            int koff = (hi < 2) ? 64 + hi * 8 : 0;
            #pragma unroll
            for (int i = 0; i < 5; i++){
                bf16x8 v = *(const bf16x8*)(Al + (i * 16 + l15) * 88 + koff);
                if (hi >= 2) v = 0;
                a[i] = v;
            }
            #pragma unroll
            for (int j = 0; j < 4; j++){
                bf16x8 v = *(const bf16x8*)(Btl + (wave * 64 + j * 16 + l15) * 88 + koff);
                if (hi >= 2) v = 0;
                bv[j] = v;
            }
        }
        #pragma unroll
        for (int i = 0; i < 5; i++)
            #pragma unroll
            for (int j = 0; j < 4; j++)
                acc[i][j] = __builtin_amdgcn_mfma_f32_16x16x32_bf16(a[i], bv[j], acc[i][j], 0, 0, 0);
    }

    #pragma unroll
    for (int i = 0; i < 5; i++){
        #pragma unroll
        for (int r = 0; r < 4; r++){
            int orow = i * 16 + hi * 4 + r;
            #pragma unroll
            for (int j = 0; j < 4; j++){
                int ocol = c0 + wave * 64 + j * 16 + l15;
                H[(size_t)b * 81920 + (size_t)orow * 1024 + ocol] =
                    __float2bfloat16(leaky(acc[i][j][r]));
            }
        }
    }
}

// ---------------- K3/K13: bf16 MFMA GEMM, 3-stage pipeline + T2 swizzle ------
// (r5 kernel, measured 77 us) 128x128 tile, BK=32, counted vmcnt(4).
template<int EPI>
__global__ __launch_bounds__(256) void k_gemm_mfma(const bf16* __restrict__ Abf,
                                                   const bf16* __restrict__ WT,
                                                   const float* __restrict__ Res,
                                                   void* __restrict__ Outv){
    __shared__ alignas(16) bf16 As[3][128 * 32];
    __shared__ alignas(16) bf16 Bs[3][128 * 32];
    const int K = 1024;
    const int NT = 32;
    int tid = threadIdx.x;
    int wave = tid >> 6, lane = tid & 63;
    int l15 = lane & 15, hi = lane >> 4;

    int bid = blockIdx.x;
    int xcd = bid & 7, idx = bid >> 3;
    int row0 = (xcd * 20 + (idx >> 3)) * 128;
    int col0 = (idx & 7) * 128;

    int sr = tid >> 2;
    int sq = (tid & 3) ^ ((tid >> 3) & 3);
    const bf16* gA = Abf + (size_t)(row0 + sr) * K + sq * 8;
    const bf16* gB = WT  + (size_t)(col0 + sr) * K + sq * 8;

    int wr = (wave >> 1) * 64, wc = (wave & 1) * 64;
    int soff = (hi ^ ((l15 >> 1) & 3)) * 8;

    f32x4 acc[4][4];
    #pragma unroll
    for (int i = 0; i < 4; i++)
        #pragma unroll
        for (int j = 0; j < 4; j++) acc[i][j] = (f32x4){0.f, 0.f, 0.f, 0.f};

    auto STAGE = [&](int t){
        int buf = t % 3;
        int k0 = t * 32;
        bf16* da = &As[buf][wave * 512];
        bf16* db = &Bs[buf][wave * 512];
        gll16(gA + k0, da);
        gll16(gA + (size_t)64 * K + k0, da + 2048);
        gll16(gB + k0, db);
        gll16(gB + (size_t)64 * K + k0, db + 2048);
    };

    STAGE(0);
    STAGE(1);
    for (int t = 0; t < NT; ++t){
        if (t == NT - 1) asm volatile("s_waitcnt vmcnt(0)" ::: "memory");
        else             asm volatile("s_waitcnt vmcnt(4)" ::: "memory");
        __builtin_amdgcn_s_barrier();
        if (t + 2 < NT) STAGE(t + 2);
        int buf = t % 3;
        const bf16* pa = &As[buf][0] + (wr + l15) * 32 + soff;
        const bf16* pb = &Bs[buf][0] + (wc + l15) * 32 + soff;
        bf16x8 a[4], b[4];
        #pragma unroll
        for (int i = 0; i < 4; i++) a[i] = *(const bf16x8*)(pa + i * 512);
        #pragma unroll
        for (int j = 0; j < 4; j++) b[j] = *(const bf16x8*)(pb + j * 512);
        __builtin_amdgcn_s_setprio(1);
        #pragma unroll
        for (int i = 0; i < 4; i++)
            #pragma unroll
            for (int j = 0; j < 4; j++)
                acc[i][j] = __builtin_amdgcn_mfma_f32_16x16x32_bf16(a[i], b[j], acc[i][j], 0, 0, 0);
        __builtin_amdgcn_s_setprio(0);
    }

    int orow = row0 + wr + hi * 4;
    int ocol = col0 + wc + l15;
    #pragma unroll
    for (int i = 0; i < 4; i++){
        #pragma unroll
        for (int r = 0; r < 4; r++){
            int rr = orow + i * 16 + r;
            #pragma unroll
            for (int j = 0; j < 4; j++){
                size_t o = (size_t)rr * 1024 + ocol + j * 16;
                float v = acc[i][j][r];
                if (EPI == 0) ((bf16*)Outv)[o] = __float2bfloat16(v + Res[o]);
                else          ((float*)Outv)[o] = leaky(v);
            }
        }
    }
}

// ---------------- K5: GLB1[b][co] = GLB0b @ cgw^T + cgb, bf16 MFMA -----------
// A=GLB0b[256][1024] (K-major), B=CGWB[1024][1024] (rows co, K-major).
// grid 16: 2 row-blocks x 8 col-blocks. Same 3-stage structure.
__global__ __launch_bounds__(256) void k_gemm_glb(const bf16* __restrict__ Abf,
                                                  const bf16* __restrict__ Bw,
                                                  const float* __restrict__ bias,
                                                  float* __restrict__ Out){
    __shared__ alignas(16) bf16 As[3][128 * 32];
    __shared__ alignas(16) bf16 Bs[3][128 * 32];
    const int K = 1024;
    const int NT = 32;
    int tid = threadIdx.x;
    int wave = tid >> 6, lane = tid & 63;
    int l15 = lane & 15, hi = lane >> 4;

    int row0 = (blockIdx.x >> 3) * 128;
    int col0 = (blockIdx.x & 7) * 128;

    int sr = tid >> 2;
    int sq = (tid & 3) ^ ((tid >> 3) & 3);
    const bf16* gA = Abf + (size_t)(row0 + sr) * K + sq * 8;
    const bf16* gB = Bw  + (size_t)(col0 + sr) * K + sq * 8;

    int wr = (wave >> 1) * 64, wc = (wave & 1) * 64;
    int soff = (hi ^ ((l15 >> 1) & 3)) * 8;

    f32x4 acc[4][4];
    #pragma unroll
    for (int i = 0; i < 4; i++)
        #pragma unroll
        for (int j = 0; j < 4; j++) acc[i][j] = (f32x4){0.f, 0.f, 0.f, 0.f};

    auto STAGE = [&](int t){
        int buf = t % 3;
        int k0 = t * 32;
        bf16* da = &As[buf][wave * 512];
        bf16* db = &Bs[buf][wave * 512];
        gll16(gA + k0, da);
        gll16(gA + (size_t)64 * K + k0, da + 2048);
        gll16(gB + k0, db);
        gll16(gB + (size_t)64 * K + k0, db + 2048);
    };

    STAGE(0);
    STAGE(1);
    for (int t = 0; t < NT; ++t){
        if (t == NT - 1) asm volatile("s_waitcnt vmcnt(0)" ::: "memory");
        else             asm volatile("s_waitcnt vmcnt(4)" ::: "memory");
        __builtin_amdgcn_s_barrier();
        if (t + 2 < NT) STAGE(t + 2);
        int buf = t % 3;
        const bf16* pa = &As[buf][0] + (wr + l15) * 32 + soff;
        const bf16* pb = &Bs[buf][0] + (wc + l15) * 32 + soff;
        bf16x8 a[4], b[4];
        #pragma unroll
        for (int i = 0; i < 4; i++) a[i] = *(const bf16x8*)(pa + i * 512);
        #pragma unroll
        for (int j = 0; j < 4; j++) b[j] = *(const bf16x8*)(pb + j * 512);
        #pragma unroll
        for (int i = 0; i < 4; i++)
            #pragma unroll
            for (int j = 0; j < 4; j++)
                acc[i][j] = __builtin_amdgcn_mfma_f32_16x16x32_bf16(a[i], b[j], acc[i][j], 0, 0, 0);
    }

    int orow = row0 + wr + hi * 4;
    int ocol = col0 + wc + l15;
    #pragma unroll
    for (int i = 0; i < 4; i++){
        #pragma unroll
        for (int r = 0; r < 4; r++){
            int rr = orow + i * 16 + r;
            #pragma unroll
            for (int j = 0; j < 4; j++){
                int cl = ocol + j * 16;
                Out[(size_t)rr * 1024 + cl] = acc[i][j][r] + bias[cl];
            }
        }
    }
}

// ---------------- K4: glb0b[b,c] = bf16(mean_n x2b[b,n,c]) ----------------
__global__ void k_pool(const bf16* __restrict__ X2b, bf16* __restrict__ glb0b){
    int b = blockIdx.x, c = blockIdx.y * 256 + threadIdx.x;
    const bf16* p = X2b + (size_t)b * 81920 + c;
    float s = 0.f;
    for (int nn = 0; nn < N_; nn++) s += __bfloat162float(p[nn * 1024]);
    glb0b[b * C_ + c] = __float2bfloat16(s * (1.f / N_));
}

// ---------------- K6: BN stats over batch (high-TLP) ----------------
__global__ __launch_bounds__(256) void k_bnstat(const float* __restrict__ g, float* __restrict__ mu,
                                                float* __restrict__ rstd){
    __shared__ float rs[8][32], rs2[8][32];
    int tid = threadIdx.x;
    int c = blockIdx.x * 32 + (tid & 31);
    int grp = tid >> 5;
    float s = 0.f, s2 = 0.f;
    for (int bb = 0; bb < 32; bb++){
        float v = g[(size_t)(grp * 32 + bb) * 1024 + c];
        s += v; s2 += v * v;
    }
    rs[grp][tid & 31] = s;
    rs2[grp][tid & 31] = s2;
    __syncthreads();
    if (tid < 32){
        float S = 0.f, S2 = 0.f;
        #pragma unroll
        for (int q = 0; q < 8; q++){ S += rs[q][tid]; S2 += rs2[q][tid]; }
        float m = S * (1.f / B_);
        float var = S2 * (1.f / B_) - m * m;
        int cc = blockIdx.x * 32 + tid;
        mu[cc] = m;
        rstd[cc] = rsqrtf(var + 1e-5f);
    }
}

// ---------------- K7: glb2b = bf16(leaky(BN(glb1))) ----------------
__global__ void k_bnapply(const float* __restrict__ g, const float* __restrict__ mu,
                          const float* __restrict__ rstd, const float* __restrict__ gamma,
                          const float* __restrict__ beta, bf16* __restrict__ o){
    int i = blockIdx.x * 256 + threadIdx.x;
    int c = i & (C_ - 1);
    float v = (g[i] - mu[c]) * rstd[c] * gamma[c] + beta[c];
    o[i] = __float2bfloat16(leaky(v));
}

// ---------------- K9: fused dyn + loss + ADJD, operand-LDS-free --------------
// dyn = sigmoid(ccw @ [glb2 ; x2[b]^T] + ccb); fragments loaded directly from
// global (ccwb L2-resident; X2b L3-resident). No barriers in K-loop.
__global__ __launch_bounds__(320) void k_dyn_fused(const bf16* __restrict__ X2b,
                                                   const bf16* __restrict__ ccwb,
                                                   const bf16* __restrict__ glb2b,
                                                   const float* __restrict__ ccb,
                                                   const float* __restrict__ out1,
                                                   bf16* __restrict__ ADJD,
                                                   float* __restrict__ lossp){
    __shared__ float S[80][81];
    __shared__ float di_s[80], o1s[80], dd[80];
    int b = blockIdx.x, tid = threadIdx.x;
    int wave = tid >> 6, lane = tid & 63;
    int l15 = lane & 15, hi = lane >> 4;

    const bf16* arow = ccwb + (size_t)(wave * 16 + l15) * 2048 + hi * 8;
    const bf16* gG = glb2b + (size_t)b * 1024 + hi * 8;
    const bf16* gX = X2b + (size_t)b * 81920 + hi * 8;

    f32x4 acc[5];
    #pragma unroll
    for (int j = 0; j < 5; j++) acc[j] = (f32x4){0.f, 0.f, 0.f, 0.f};

    // first half: B = broadcast glb2 vector
    #pragma unroll 8
    for (int k0 = 0; k0 < 1024; k0 += 32){
        bf16x8 a = *(const bf16x8*)(arow + k0);
        bf16x8 g = *(const bf16x8*)(gG + k0);
        #pragma unroll
        for (int j = 0; j < 5; j++)
            acc[j] = __builtin_amdgcn_mfma_f32_16x16x32_bf16(a, g, acc[j], 0, 0, 0);
    }
    // second half: B rows from X2b
    #pragma unroll 4
    for (int k0 = 0; k0 < 1024; k0 += 32){
        bf16x8 a = *(const bf16x8*)(arow + 1024 + k0);
        #pragma unroll
        for (int j = 0; j < 5; j++){
            bf16x8 bv = *(const bf16x8*)(gX + (size_t)(j * 16 + l15) * 1024 + k0);
            acc[j] = __builtin_amdgcn_mfma_f32_16x16x32_bf16(a, bv, acc[j], 0, 0, 0);
        }
    }

    #pragma unroll
    for (int r = 0; r < 4; r++){
        int n = wave * 16 + hi * 4 + r;
        float cb = ccb[n];
        #pragma unroll
        for (int j = 0; j < 5; j++)
            S[n][j * 16 + l15] = sigmoidf_(acc[j][r] + cb);
    }
    __syncthreads();
    if (tid < 80){
        float rsum = 0.f;
        for (int m = 0; m < 80; m++) rsum += S[tid][m];
        di_s[tid] = rsqrtf(rsum);
        o1s[tid] = sigmoidf_(out1[b * 80 + tid]);
    }
    __syncthreads();
    if (tid < 80){
        float cs = 0.f;
        for (int n = 0; n < 80; n++) cs += o1s[n] * S[n][tid];
        float diff = o1s[tid] - cs * (1.f / 80.f);
        dd[tid] = diff * diff;
    }
    __syncthreads();
    if (tid == 0){
        float s = 0.f;
        for (int m = 0; m < 80; m++) s += dd[m];
        lossp[b] = sqrtf(s);
    }
    bf16* ab = ADJD + (size_t)b * 80 * 88;
    for (int idx = tid; idx < 6400; idx += 320){
        int n = idx / 80, m = idx - n * 80;
        ab[n * 88 + m] = __float2bfloat16(di_s[n] * S[m][n] * di_s[m]);
    }
}

// ---------------- K11: loss = sum(lossp) ----------------
__global__ void k_lsum(const float* __restrict__ lossp, float* __restrict__ out_loss){
    float v = lossp[threadIdx.x];
    for (int off = 32; off; off >>= 1) v += __shfl_down(v, off);
    __shared__ float wsum[4];
    int lane = threadIdx.x & 63, w = threadIdx.x >> 6;
    if (lane == 0) wsum[w] = v;
    __syncthreads();
    if (threadIdx.x == 0) out_loss[0] = wsum[0] + wsum[1] + wsum[2] + wsum[3];
}

extern "C" void kernel_launch(void* const* d_in, const int* in_sizes, int n_in,
                              void* d_out, int out_size, void* d_ws, size_t ws_size,
                              hipStream_t stream) {
    const float* x     = (const float*)d_in[0];
    const float* out1  = (const float*)d_in[1];
    const float* A     = (const float*)d_in[2];
    const float* sw    = (const float*)d_in[3];
    const float* cgw   = (const float*)d_in[4];
    const float* cgb   = (const float*)d_in[5];
    const float* gamma = (const float*)d_in[6];
    const float* beta  = (const float*)d_in[7];
    const float* ccw   = (const float*)d_in[8];
    const float* ccb   = (const float*)d_in[9];
    const float* dw    = (const float*)d_in[10];
    float* out = (float*)d_out;

    const size_t XN = (size_t)B_ * N_ * C_;   // 20,971,520
    char* p = (char*)d_ws;
    bf16*  Hbf  = (bf16*)p;   p += XN * 2;               // 42 MB
    bf16*  X2b  = (bf16*)p;   p += XN * 2;               // 42 MB
    bf16*  SWT  = (bf16*)p;   p += (size_t)C_ * C_ * 2;  // 2 MB
    bf16*  DWT  = (bf16*)p;   p += (size_t)C_ * CO_ * 2; // 2 MB
    bf16*  CCWB = (bf16*)p;   p += (size_t)N_ * 2048 * 2;
    bf16*  CGWB = (bf16*)p;   p += (size_t)C_ * C_ * 2;  // 2 MB
    bf16*  ADJS = (bf16*)p;   p += (size_t)80 * 88 * 2;
    bf16*  ADJD = (bf16*)p;   p += (size_t)B_ * 80 * 88 * 2;  // 3.6 MB
    bf16*  GLB0 = (bf16*)p;   p += (size_t)B_ * C_ * 2;
    float* GLB1 = (float*)p;  p += (size_t)B_ * C_ * 4;
    bf16*  GLB2 = (bf16*)p;   p += (size_t)B_ * C_ * 2;
    float* MU   = (float*)p;  p += C_ * 4;
    float* RSTD = (float*)p;  p += C_ * 4;
    float* LOSSP= (float*)p;  p += B_ * 4;

    k_convT2<<<dim3(32, 32, 2), 256, 0, stream>>>(sw, dw, SWT, DWT);
    k_cvt_ccw<<<(N_ * 2048) / 256, 256, 0, stream>>>(ccw, CCWB);
    k_cvt4<<<(C_ * C_) / 1024, 256, 0, stream>>>(cgw, CGWB);
    k_adj<<<1, 256, 0, stream>>>(A, ADJS);
    k_prop_mfma<0><<<dim3(B_, 4), 256, 0, stream>>>(x, ADJS, Hbf);
    k_gemm_mfma<0><<<1280, 256, 0, stream>>>(Hbf, SWT, x, X2b);
    k_pool<<<dim3(B_, C_ / 256), 256, 0, stream>>>(X2b, GLB0);
    k_gemm_glb<<<16, 256, 0, stream>>>(GLB0, CGWB, cgb, GLB1);
    k_bnstat<<<32, 256, 0, stream>>>(GLB1, MU, RSTD);
    k_bnapply<<<(B_ * C_) / 256, 256, 0, stream>>>(GLB1, MU, RSTD, gamma, beta, GLB2);
    k_dyn_fused<<<B_, 320, 0, stream>>>(X2b, CCWB, GLB2, ccb, out1, ADJD, LOSSP);
    k_lsum<<<1, 256, 0, stream>>>(LOSSP, out + (size_t)B_ * N_ * CO_);
    k_prop_mfma<1><<<dim3(B_, 4), 256, 0, stream>>>(X2b, ADJD, Hbf);
    k_gemm_mfma<1><<<1280, 256, 0, stream>>>(Hbf, DWT, nullptr, out);
}